// Round 4
// baseline (3398.109 us; speedup 1.0000x reference)
//
#include <hip/hip_runtime.h>
#include <hip/hip_bf16.h>
#include <math.h>

typedef unsigned short u16;
typedef unsigned int   u32;
typedef __attribute__((ext_vector_type(8))) short short8;
typedef __attribute__((ext_vector_type(4))) float f32x4;

#define DEV __device__ __forceinline__

DEV float bf2f(u16 x){ u32 u = ((u32)x) << 16; return __builtin_bit_cast(float, u); }
DEV u16 f2bf(float f){ u32 u = __builtin_bit_cast(u32, f); u32 r = (u + 0x7fffu + ((u >> 16) & 1u)) >> 16; return (u16)r; }
DEV float sigf(float x){ return 1.0f / (1.0f + expf(-x)); }
// dual-dtype input load: inputs are fp32 or bf16 depending on runtime flag
DEV float ldIn(const void* p, size_t i, bool f32){
    return f32 ? ((const float*)p)[i] : bf2f(((const u16*)p)[i]);
}

// -------------------------------------------------------------- k_detect ----
// Interpret first 4096 u16 of prefix_emb as bf16. N(0,1) bf16 data never has
// exponent >= 0x90 (|v| >= 2^17); fp32 data's mantissa halves hit it w.p. ~44%
// per even element. Sets flag=1 for fp32 inputs. Also zeroes spin counters.
__global__ void k_detect(const u16* __restrict__ pemb, u32* __restrict__ flag,
                         u32* __restrict__ cnt)
{
    __shared__ int s;
    if (threadIdx.x == 0) s = 0;
    __syncthreads();
    for (int i = threadIdx.x; i < 4096; i += 256) {
        u16 v = pemb[i];
        int e = (v >> 7) & 0xFF;
        if (e >= 0x90) s = 1;
    }
    __syncthreads();
    if (threadIdx.x == 0) flag[0] = (u32)s;
    if (threadIdx.x < 8) cnt[threadIdx.x] = 0u;
}

// ---------------------------------------------------------------- k_init ----
// Build X[4][64][1024] bf16: chains 0,1 = prefix,suffix (+PE); chains 2,3 flipped.
__global__ void k_init(const void* __restrict__ pemb, const void* __restrict__ semb,
                       u16* __restrict__ X, const u32* __restrict__ dflag)
{
    bool f32 = dflag[0] != 0u;
    int idx = blockIdx.x * 256 + threadIdx.x;      // 4*64*1024 = 262144
    int c = idx >> 16;
    int rem = idx & 65535;
    int t = rem >> 10;
    int k = rem & 1023;
    int tsrc = (c < 2) ? t : (63 - t);
    float div = expf(-9.210340371976184f * (float)(k & ~1) / 1024.0f);
    float ang = (float)tsrc * div;
    float pe = (k & 1) ? cosf(ang) : sinf(ang);
    const void* e = (c & 1) ? semb : pemb;
    float v = ldIn(e, (size_t)tsrc * 1024 + k, f32) + pe;
    X[idx] = f2bf(v);
}

// ---------------------------------------------------------------- k_gemm ----
// Generic small-M GEMM: O[b][m][n] = sum_k A[b][m][k]*W[Woff[b] + n*K + k]
//                                  + b1[b1off[b]+n] (+ b2[b2off[b]+n])
// M = 64 fixed. A is internal bf16; W/b1/b2 are raw inputs (flag-typed). fp32 out.
// One WG = 4 waves, each wave a 64x16 output tile via mfma 16x16x32.
struct GemmArgs {
    const u16* A[8];
    float* O[8];
    size_t Woff[8], b1off[8], b2off[8];
    int hasb2;
    const void *Wb, *b1b, *b2b;
    const u32* flag;
    int N, K, tiles;   // tiles = N/64
};

__global__ __launch_bounds__(256) void k_gemm(GemmArgs g)
{
    bool f32 = g.flag[0] != 0u;
    int b  = blockIdx.x / g.tiles;
    int n0 = (blockIdx.x % g.tiles) * 64;
    int wave = threadIdx.x >> 6, lane = threadIdx.x & 63;
    int ncol = n0 + wave * 16 + (lane & 15);
    int krow = (lane >> 4) * 8;
    const int K = g.K, N = g.N;
    const u16* ap = g.A[b] + (size_t)(lane & 15) * K + krow;
    size_t welem = g.Woff[b] + (size_t)ncol * K + krow;
    const u16*   wp  = ((const u16*)g.Wb)   + welem;
    const float* wpf = ((const float*)g.Wb) + welem;
    f32x4 acc[4] = {};
    for (int k = 0; k < K; k += 32) {
        short8 bfrag;
        if (!f32) {
            bfrag = *(const short8*)(wp + k);
        } else {
            const float* s = wpf + k;
            #pragma unroll
            for (int e = 0; e < 8; e++) bfrag[e] = (short)f2bf(s[e]);
        }
        #pragma unroll
        for (int mt = 0; mt < 4; mt++) {
            short8 afrag = *(const short8*)(ap + (size_t)mt * 16 * K + k);
            acc[mt] = __builtin_amdgcn_mfma_f32_16x16x32_bf16(afrag, bfrag, acc[mt], 0, 0, 0);
        }
    }
    float bias = ldIn(g.b1b, g.b1off[b] + ncol, f32)
               + (g.hasb2 ? ldIn(g.b2b, g.b2off[b] + ncol, f32) : 0.0f);
    float* O = g.O[b];
    #pragma unroll
    for (int mt = 0; mt < 4; mt++) {
        #pragma unroll
        for (int r = 0; r < 4; r++) {
            int m = mt * 16 + (lane >> 4) * 4 + r;
            O[(size_t)m * N + ncol] = acc[mt][r] + bias;
        }
    }
}

// ----------------------------------------------------------------- k_rec ----
// Persistent LSTM recurrence, one layer. 4 groups (lstm-module m x dir d) x 32 WGs.
// Each WG owns 16 h-indices (64 z-rows), Whh slice pre-unpacked into VGPRs.
// h exchanged via ping-pong global buffer, per-group atomic arrival counter.
__global__ __launch_bounds__(256, 1) void k_rec(const void* __restrict__ WhhV,
        const float* __restrict__ IH, float* __restrict__ hbuf,
        u32* __restrict__ cnt, u16* __restrict__ Y, int layer,
        const u32* __restrict__ dflag)
{
    bool f32 = dflag[0] != 0u;
    const int tid = threadIdx.x;
    const int g   = blockIdx.x >> 5;     // 0..3  (m = g>>1, d = g&1)
    const int w   = blockIdx.x & 31;     // WG within group: h-indices [w*16, w*16+16)
    const int m_  = g >> 1, d = g & 1;
    u32* cg = cnt + g;

    __shared__ __align__(16) float lds_h[1024];     // [2 chains][512]
    __shared__ __align__(16) float zp[64 * 8 * 2];  // [row64][kq8][ch2]
    __shared__ float zfin[128];                     // [ch2][row64]

    // --- weight slice -> registers ---
    const int kq = tid & 7;        // k slice [kq*64, kq*64+64)
    const int rp = tid >> 3;       // row pair
    const int lr0 = rp * 2, lr1 = rp * 2 + 1;
    const size_t wbase = (size_t)((m_ * 2 + layer) * 2 + d) * 2048 * 512;
    float wf0[64], wf1[64];
    {
        int grow0 = (lr0 >> 4) * 512 + w * 16 + (lr0 & 15);
        int grow1 = (lr1 >> 4) * 512 + w * 16 + (lr1 & 15);
        size_t o0 = wbase + (size_t)grow0 * 512 + kq * 64;
        size_t o1 = wbase + (size_t)grow1 * 512 + kq * 64;
        if (!f32) {
            const u16* s0 = (const u16*)WhhV + o0;
            const u16* s1 = (const u16*)WhhV + o1;
            #pragma unroll
            for (int j8 = 0; j8 < 8; j8++) {
                short8 v0 = *(const short8*)(s0 + j8 * 8);
                short8 v1 = *(const short8*)(s1 + j8 * 8);
                #pragma unroll
                for (int e = 0; e < 8; e++) {
                    wf0[j8 * 8 + e] = bf2f((u16)v0[e]);
                    wf1[j8 * 8 + e] = bf2f((u16)v1[e]);
                }
            }
        } else {
            const float* s0 = (const float*)WhhV + o0;
            const float* s1 = (const float*)WhhV + o1;
            #pragma unroll
            for (int j = 0; j < 64; j++) { wf0[j] = s0[j]; wf1[j] = s1[j]; }
        }
    }
    float cst = 0.0f;   // cell state (threads tid<32: ch=tid>>4, hh=tid&15)

    // zero ping buffer 0 (our slice), announce
    if (tid < 32) {
        int ch = tid >> 4, hh = tid & 15;
        hbuf[(0 * 4 + g) * 1024 + ch * 512 + w * 16 + hh] = 0.0f;
    }
    __threadfence();
    __syncthreads();
    if (tid == 0) __hip_atomic_fetch_add(cg, 1u, __ATOMIC_RELEASE, __HIP_MEMORY_SCOPE_AGENT);
    u32 phase = 1;

    for (int s = 0; s < 64; s++) {
        int t = d ? (63 - s) : s;
        if (tid == 0) {
            u32 target = 32u * phase;
            while (__hip_atomic_load(cg, __ATOMIC_RELAXED, __HIP_MEMORY_SCOPE_AGENT) < target)
                __builtin_amdgcn_s_sleep(1);
        }
        __syncthreads();
        __threadfence();   // acquire: invalidate stale cache before reading h
        {
            const float* hb = hbuf + ((s & 1) * 4 + g) * 1024;
            *(float4*)(&lds_h[tid * 4]) = *(const float4*)(hb + tid * 4);
        }
        __syncthreads();

        // --- partial dots: 2 rows x 2 chains x 64 k ---
        float a00 = 0, a01 = 0, a10 = 0, a11 = 0;
        {
            const float4* h0 = (const float4*)(lds_h + kq * 64);
            const float4* h1 = (const float4*)(lds_h + 512 + kq * 64);
            #pragma unroll
            for (int j4 = 0; j4 < 16; j4++) {
                float4 hv0 = h0[j4], hv1 = h1[j4];
                int j = j4 * 4;
                a00 += wf0[j]*hv0.x + wf0[j+1]*hv0.y + wf0[j+2]*hv0.z + wf0[j+3]*hv0.w;
                a01 += wf0[j]*hv1.x + wf0[j+1]*hv1.y + wf0[j+2]*hv1.z + wf0[j+3]*hv1.w;
                a10 += wf1[j]*hv0.x + wf1[j+1]*hv0.y + wf1[j+2]*hv0.z + wf1[j+3]*hv0.w;
                a11 += wf1[j]*hv1.x + wf1[j+1]*hv1.y + wf1[j+2]*hv1.z + wf1[j+3]*hv1.w;
            }
        }
        zp[(lr0 * 8 + kq) * 2 + 0] = a00; zp[(lr0 * 8 + kq) * 2 + 1] = a01;
        zp[(lr1 * 8 + kq) * 2 + 0] = a10; zp[(lr1 * 8 + kq) * 2 + 1] = a11;
        __syncthreads();

        // --- combine + add ih ---
        if (tid < 128) {
            int ch = tid >> 6, lr = tid & 63;
            float z = 0;
            #pragma unroll
            for (int q8 = 0; q8 < 8; q8++) z += zp[(lr * 8 + q8) * 2 + ch];
            int b = (2 * m_ + ch) * 2 + d;
            int row = (lr >> 4) * 512 + w * 16 + (lr & 15);
            z += IH[((size_t)(b * 64 + t)) * 2048 + row];
            zfin[ch * 64 + lr] = z;
        }
        __syncthreads();

        // --- gate update ---
        if (tid < 32) {
            int ch = tid >> 4, hh = tid & 15;
            float zi = zfin[ch * 64 + hh];
            float zf = zfin[ch * 64 + 16 + hh];
            float zg = zfin[ch * 64 + 32 + hh];
            float zo = zfin[ch * 64 + 48 + hh];
            cst = sigf(zf) * cst + sigf(zi) * tanhf(zg);
            float hv = sigf(zo) * tanhf(cst);
            hbuf[(((s + 1) & 1) * 4 + g) * 1024 + ch * 512 + w * 16 + hh] = hv;
            Y[(size_t)(2 * m_ + ch) * 65536 + (size_t)t * 1024 + d * 512 + w * 16 + hh] = f2bf(hv);
        }
        __threadfence();
        __syncthreads();
        if (tid == 0) __hip_atomic_fetch_add(cg, 1u, __ATOMIC_RELEASE, __HIP_MEMORY_SCOPE_AGENT);
        phase++;
    }
}

// ---------------------------------------------------------------- k_pack ----
// Gcat[g][t][0:1024] = Y1[chain g][t]; Gcat[g][t][1024:2048] = Y1[chain g+2][63-t]
__global__ void k_pack(const u16* __restrict__ Y1, u16* __restrict__ GCAT)
{
    int idx = blockIdx.x * 256 + threadIdx.x;     // 2*64*2048
    int g = idx >> 17;
    int rem = idx & 131071;
    int t = rem >> 11;
    int k = rem & 2047;
    u16 v;
    if (k < 1024) v = Y1[(size_t)g * 65536 + (size_t)t * 1024 + k];
    else          v = Y1[(size_t)(g + 2) * 65536 + (size_t)(63 - t) * 1024 + (k - 1024)];
    GCAT[idx] = v;
}

// ------------------------------------------------------------- row stats ----
DEV void rowStats(const float* x, int Nf, float& mean, float& inv)
{
    float s = 0, ss = 0;
    for (int i = threadIdx.x; i < Nf; i += 256) { float v = x[i]; s += v; ss += v * v; }
    for (int o = 32; o > 0; o >>= 1) { s += __shfl_down(s, o, 64); ss += __shfl_down(ss, o, 64); }
    __shared__ float red[8];
    int wave = threadIdx.x >> 6, lane = threadIdx.x & 63;
    if (lane == 0) { red[wave] = s; red[4 + wave] = ss; }
    __syncthreads();
    s  = red[0] + red[1] + red[2] + red[3];
    ss = red[4] + red[5] + red[6] + red[7];
    mean = s / (float)Nf;
    float var = ss / (float)Nf - mean * mean;
    inv = 1.0f / sqrtf(var + 1e-5f);
    __syncthreads();
}

// ------------------------------------------------------------- k_lngelu -----
// out[row] = gelu(LN(x[row]) * g + b)  (per-batch g/b at (row>>6)*Nf)
__global__ __launch_bounds__(256) void k_lngelu(const float* __restrict__ X,
        const void* __restrict__ gg, const void* __restrict__ bb,
        u16* __restrict__ out, int Nf, const u32* __restrict__ dflag)
{
    bool f32 = dflag[0] != 0u;
    int row = blockIdx.x;
    const float* xr = X + (size_t)row * Nf;
    size_t gbase = (size_t)(row >> 6) * Nf;
    float mean, inv;
    rowStats(xr, Nf, mean, inv);
    for (int i = threadIdx.x; i < Nf; i += 256) {
        float y = (xr[i] - mean) * inv * ldIn(gg, gbase + i, f32) + ldIn(bb, gbase + i, f32);
        float a = 0.5f * y * (1.0f + erff(y * 0.70710678118654752f));
        out[(size_t)row * Nf + i] = f2bf(a);
    }
}

// ----------------------------------------------------------- k_gatecomb -----
__global__ void k_gatecomb(const float* __restrict__ GZ, const u16* __restrict__ GCAT,
                           u16* __restrict__ BI)
{
    int idx = blockIdx.x * 256 + threadIdx.x;   // 2*64*1024
    int g = idx >> 16;
    int rem = idx & 65535;
    int t = rem >> 10;
    int k = rem & 1023;
    const float* zr = GZ + (size_t)(g * 64 + t) * 2048;
    const u16* gr = GCAT + (size_t)(g * 64 + t) * 2048;
    float v = sigf(zr[k]) * bf2f(gr[k]) + sigf(zr[1024 + k]) * bf2f(gr[1024 + k]);
    BI[idx] = f2bf(v);
}

// ---------------------------------------------------------------- k_attn ----
// One WG per (a, head). QKV fp32 [6][64][1024]; writes AO bf16 [2][64][1024].
__global__ __launch_bounds__(256) void k_attn(const float* __restrict__ QKV, u16* __restrict__ AO)
{
    int a = blockIdx.x >> 3;
    int h = blockIdx.x & 7;
    int tid = threadIdx.x;
    __shared__ u16 kls[64 * 136];
    __shared__ u16 vls[64 * 136];
    __shared__ float sls[64 * 66];

    for (int idx = tid; idx < 8192; idx += 256) {
        int n = idx >> 7, dd = idx & 127;
        kls[n * 136 + dd] = f2bf(QKV[((size_t)((a * 3 + 1) * 64 + n)) * 1024 + h * 128 + dd]);
        vls[n * 136 + dd] = f2bf(QKV[((size_t)((a * 3 + 2) * 64 + n)) * 1024 + h * 128 + dd]);
    }
    __syncthreads();

    // scores
    {
        int n = tid >> 2, ms = tid & 3;
        const float* qrow = QKV + ((size_t)((a * 3 + 0) * 64 + n)) * 1024 + h * 128;
        float4 qreg[32];
        #pragma unroll
        for (int q4 = 0; q4 < 32; q4++) qreg[q4] = *(const float4*)(qrow + q4 * 4);
        for (int j = 0; j < 16; j++) {
            int m = ms * 16 + j;
            const u16* kr = kls + m * 136;
            float acc = 0;
            #pragma unroll
            for (int q4 = 0; q4 < 32; q4++) {
                u32 k01 = *(const u32*)(kr + q4 * 4);
                u32 k23 = *(const u32*)(kr + q4 * 4 + 2);
                float4 qv = qreg[q4];
                acc += qv.x * bf2f((u16)(k01 & 0xffff)) + qv.y * bf2f((u16)(k01 >> 16))
                     + qv.z * bf2f((u16)(k23 & 0xffff)) + qv.w * bf2f((u16)(k23 >> 16));
            }
            sls[n * 66 + m] = acc * 0.08838834764831845f;   // 1/sqrt(128)
        }
    }
    __syncthreads();
    if (tid < 64) {
        float mx = -1e30f;
        for (int m = 0; m < 64; m++) mx = fmaxf(mx, sls[tid * 66 + m]);
        float sum = 0;
        for (int m = 0; m < 64; m++) { float e = expf(sls[tid * 66 + m] - mx); sls[tid * 66 + m] = e; sum += e; }
        float r = 1.0f / sum;
        for (int m = 0; m < 64; m++) sls[tid * 66 + m] *= r;
    }
    __syncthreads();
    // PV
    {
        int n = tid & 63, db = tid >> 6;
        float acc[32] = {};
        for (int m = 0; m < 64; m++) {
            float p = sls[n * 66 + m];
            const u16* vr = vls + m * 136 + db * 32;
            #pragma unroll
            for (int jj = 0; jj < 16; jj++) {
                u32 vv = *(const u32*)(vr + jj * 2);
                acc[2 * jj]     += p * bf2f((u16)(vv & 0xffff));
                acc[2 * jj + 1] += p * bf2f((u16)(vv >> 16));
            }
        }
        #pragma unroll
        for (int dd = 0; dd < 32; dd++)
            AO[((size_t)(a * 64 + n)) * 1024 + h * 128 + db * 32 + dd] = f2bf(acc[dd]);
    }
}

// --------------------------------------------------------------- k_resln ----
__global__ __launch_bounds__(256) void k_resln(const u16* __restrict__ BI, const float* __restrict__ PA,
        const void* __restrict__ lg, const void* __restrict__ lb,
        u16* __restrict__ RO, const u32* __restrict__ dflag)
{
    bool f32 = dflag[0] != 0u;
    int row = blockIdx.x;   // 0..127
    __shared__ __align__(16) float xb[1024];
    for (int i = threadIdx.x; i < 1024; i += 256)
        xb[i] = bf2f(BI[(size_t)row * 1024 + i]) + PA[(size_t)row * 1024 + i];
    __syncthreads();
    float mean, inv;
    rowStats(xb, 1024, mean, inv);
    for (int i = threadIdx.x; i < 1024; i += 256) {
        float y = (xb[i] - mean) * inv * ldIn(lg, i, f32) + ldIn(lb, i, f32);
        RO[(size_t)row * 1024 + i] = f2bf(y);
    }
}

// --------------------------------------------------------------- k_final ----
// LN(T2; g2, be2) then broadcast to all 64 batch rows of d_out.
// Output dtype follows the input dtype flag: fp32 inputs => fp32 output.
__global__ __launch_bounds__(256) void k_final(const float* __restrict__ T2,
        const void* __restrict__ g2, const void* __restrict__ be2,
        void* __restrict__ dout, const u32* __restrict__ dflag)
{
    bool f32 = dflag[0] != 0u;
    int row = blockIdx.x;         // 0..127  (i = row>>6, t = row&63)
    int i = row >> 6, trow = row & 63;
    const float* xr = T2 + (size_t)row * 1024;
    float mean, inv;
    rowStats(xr, 1024, mean, inv);
    __shared__ __align__(16) float lrow[1024];
    for (int k = threadIdx.x; k < 1024; k += 256) {
        float y = (xr[k] - mean) * inv * ldIn(g2, (size_t)i * 1024 + k, f32)
                + ldIn(be2, (size_t)i * 1024 + k, f32);
        lrow[k] = y;
    }
    __syncthreads();
    size_t base = (size_t)i * 4194304 + (size_t)trow * 1024 + threadIdx.x * 4;
    if (f32) {
        float4 val = *(const float4*)(lrow + threadIdx.x * 4);
        float* df = (float*)dout;
        for (int b = 0; b < 64; b++)
            *(float4*)(df + base + (size_t)b * 65536) = val;
    } else {
        ushort4 val;
        val.x = f2bf(lrow[threadIdx.x * 4 + 0]);
        val.y = f2bf(lrow[threadIdx.x * 4 + 1]);
        val.z = f2bf(lrow[threadIdx.x * 4 + 2]);
        val.w = f2bf(lrow[threadIdx.x * 4 + 3]);
        u16* du = (u16*)dout;
        for (int b = 0; b < 64; b++)
            *(ushort4*)(du + base + (size_t)b * 65536) = val;
    }
}

// ------------------------------------------------------------------ host ----
extern "C" void kernel_launch(void* const* d_in, const int* in_sizes, int n_in,
                              void* d_out, int out_size, void* d_ws, size_t ws_size,
                              hipStream_t stream)
{
    const void* pemb = d_in[0];
    const void* semb = d_in[1];
    const void* Wih  = d_in[2];
    const void* Whh  = d_in[3];
    const void* bih  = d_in[4];
    const void* bhh  = d_in[5];
    const void* attw = d_in[6];
    const void* attb = d_in[7];
    const void* gw1  = d_in[8];
    const void* gb1  = d_in[9];
    const void* glg  = d_in[10];
    const void* glb  = d_in[11];
    const void* gw2  = d_in[12];
    const void* gb2  = d_in[13];
    const void* ow1  = d_in[14];
    const void* ob1  = d_in[15];
    const void* og1  = d_in[16];
    const void* obe1 = d_in[17];
    const void* ow2  = d_in[18];
    const void* ob2  = d_in[19];
    const void* og2  = d_in[20];
    const void* obe2 = d_in[21];
    const void* lng  = d_in[22];
    const void* lnb  = d_in[23];

    char* wsb = (char*)d_ws;
    u32*   cnt  = (u32*)  (wsb + 0);           //  8 u32
    u32*   dflag= (u32*)  (wsb + 64);          //  1 u32
    float* hbuf = (float*)(wsb + 256);         //  32 KB (2 pp x 4 g x 1024)
    u16*   X    = (u16*)  (wsb + 33024);       //  4x64x1024 bf16
    u16*   Y0   = (u16*)  (wsb + 557312);
    u16*   Y1   = (u16*)  (wsb + 1081600);
    float* IHf  = (float*)(wsb + 1605888);     //  8x64x2048 f32
    u16*   GCAT = (u16*)  (wsb + 5800192);     //  2x64x2048 bf16
    float* H1   = (float*)(wsb + 6324480);     //  2x64x1024 f32
    u16*   H1G  = (u16*)  (wsb + 6848768);
    float* GZ   = (float*)(wsb + 7110912);     //  2x64x2048 f32
    u16*   BI   = (u16*)  (wsb + 8159488);
    float* QKVf = (float*)(wsb + 8421632);     //  6x64x1024 f32
    u16*   AO   = (u16*)  (wsb + 9994496);
    float* PA   = (float*)(wsb + 10256640);
    u16*   RO   = (u16*)  (wsb + 10780928);
    float* T1   = (float*)(wsb + 11043072);    //  2x64x2048 f32
    u16*   T1G  = (u16*)  (wsb + 12091648);
    float* T2   = (float*)(wsb + 12615936);

    auto launch_gemm = [&](int N, int K, int tiles, int nb,
                           const u16* const* Aps,
                           const void* Wbase, const size_t* Woff,
                           const void* b1base, const size_t* b1off,
                           const void* b2base, const size_t* b2off,
                           float* const* Ops)
    {
        GemmArgs ga;
        ga.N = N; ga.K = K; ga.tiles = tiles; ga.flag = dflag;
        ga.Wb = Wbase; ga.b1b = b1base; ga.b2b = b2base;
        ga.hasb2 = (b2base != nullptr) ? 1 : 0;
        for (int b = 0; b < nb; b++) {
            ga.A[b] = Aps[b]; ga.O[b] = Ops[b];
            ga.Woff[b] = Woff[b];
            ga.b1off[b] = b1off[b];
            ga.b2off[b] = b2off ? b2off[b] : 0;
        }
        for (int b = nb; b < 8; b++) {
            ga.A[b] = Aps[0]; ga.O[b] = Ops[0];
            ga.Woff[b] = 0; ga.b1off[b] = 0; ga.b2off[b] = 0;
        }
        k_gemm<<<dim3(nb * tiles), dim3(256), 0, stream>>>(ga);
    };

    // 0) dtype detect + counter zero
    k_detect<<<dim3(1), dim3(256), 0, stream>>>((const u16*)pemb, dflag, cnt);

    // 1) embeddings + PE
    k_init<<<dim3(1024), dim3(256), 0, stream>>>(pemb, semb, X, dflag);

    // 2) layer-0 input GEMMs  (8: chain c x dir d)
    {
        const u16* Aps[8]; float* Ops[8]; size_t Woff[8], b1off[8], b2off[8];
        for (int b = 0; b < 8; b++) {
            int c = b >> 1, d = b & 1, m = c >> 1;
            size_t widx = (size_t)(m * 2 + 0) * 2 + d;
            Aps[b] = X + (size_t)c * 65536;
            Woff[b] = widx * 2048 * 1024;
            b1off[b] = widx * 2048;
            b2off[b] = widx * 2048;
            Ops[b] = IHf + (size_t)b * 131072;
        }
        launch_gemm(2048, 1024, 32, 8, Aps, Wih, Woff, bih, b1off, bhh, b2off, Ops);
    }
    // 3) layer-0 recurrence
    k_rec<<<dim3(128), dim3(256), 0, stream>>>(Whh, IHf, hbuf, cnt + 0, Y0, 0, dflag);

    // 4) layer-1 input GEMMs
    {
        const u16* Aps[8]; float* Ops[8]; size_t Woff[8], b1off[8], b2off[8];
        for (int b = 0; b < 8; b++) {
            int c = b >> 1, d = b & 1, m = c >> 1;
            size_t widx = (size_t)(m * 2 + 1) * 2 + d;
            Aps[b] = Y0 + (size_t)c * 65536;
            Woff[b] = widx * 2048 * 1024;
            b1off[b] = widx * 2048;
            b2off[b] = widx * 2048;
            Ops[b] = IHf + (size_t)b * 131072;
        }
        launch_gemm(2048, 1024, 32, 8, Aps, Wih, Woff, bih, b1off, bhh, b2off, Ops);
    }
    // 5) layer-1 recurrence
    k_rec<<<dim3(128), dim3(256), 0, stream>>>(Whh, IHf, hbuf, cnt + 4, Y1, 1, dflag);

    // 6) gate stage
    k_pack<<<dim3(1024), dim3(256), 0, stream>>>(Y1, GCAT);
    {
        const u16* Aps[2]; float* Ops[2]; size_t Woff[2], b1off[2];
        for (int b = 0; b < 2; b++) {
            Aps[b] = GCAT + (size_t)b * 131072;
            Woff[b] = (size_t)b * 2097152;
            b1off[b] = (size_t)b * 1024;
            Ops[b] = H1 + (size_t)b * 65536;
        }
        launch_gemm(1024, 2048, 16, 2, Aps, gw1, Woff, gb1, b1off, nullptr, nullptr, Ops);
    }
    k_lngelu<<<dim3(128), dim3(256), 0, stream>>>(H1, glg, glb, H1G, 1024, dflag);
    {
        const u16* Aps[2]; float* Ops[2]; size_t Woff[2], b1off[2];
        for (int b = 0; b < 2; b++) {
            Aps[b] = H1G + (size_t)b * 65536;
            Woff[b] = (size_t)b * 2097152;
            b1off[b] = (size_t)b * 2048;
            Ops[b] = GZ + (size_t)b * 131072;
        }
        launch_gemm(2048, 1024, 32, 2, Aps, gw2, Woff, gb2, b1off, nullptr, nullptr, Ops);
    }
    k_gatecomb<<<dim3(512), dim3(256), 0, stream>>>(GZ, GCAT, BI);

    // 7) cross attention
    {
        const u16* Aps[6]; float* Ops[6]; size_t Woff[6], b1off[6];
        for (int aa = 0; aa < 2; aa++) for (int wch = 0; wch < 3; wch++) {
            int b = aa * 3 + wch;
            Aps[b] = BI + (size_t)((wch == 0) ? aa : (1 - aa)) * 65536;
            Woff[b] = (size_t)(aa * 4 + wch) * 1048576;
            b1off[b] = (size_t)(aa * 4 + wch) * 1024;
            Ops[b] = QKVf + (size_t)b * 65536;
        }
        launch_gemm(1024, 1024, 16, 6, Aps, attw, Woff, attb, b1off, nullptr, nullptr, Ops);
    }
    k_attn<<<dim3(16), dim3(256), 0, stream>>>(QKVf, AO);
    {
        const u16* Aps[2]; float* Ops[2]; size_t Woff[2], b1off[2];
        for (int b = 0; b < 2; b++) {
            Aps[b] = AO + (size_t)b * 65536;
            Woff[b] = (size_t)(b * 4 + 3) * 1048576;
            b1off[b] = (size_t)(b * 4 + 3) * 1024;
            Ops[b] = PA + (size_t)b * 65536;
        }
        launch_gemm(1024, 1024, 16, 2, Aps, attw, Woff, attb, b1off, nullptr, nullptr, Ops);
    }
    k_resln<<<dim3(128), dim3(256), 0, stream>>>(BI, PA, lng, lnb, RO, dflag);

    // 8) output transforms
    {
        const u16* Aps[2]; float* Ops[2]; size_t Woff[2], b1off[2];
        for (int b = 0; b < 2; b++) {
            Aps[b] = RO + (size_t)b * 65536;
            Woff[b] = (size_t)b * 2097152;
            b1off[b] = (size_t)b * 2048;
            Ops[b] = T1 + (size_t)b * 131072;
        }
        launch_gemm(2048, 1024, 32, 2, Aps, ow1, Woff, ob1, b1off, nullptr, nullptr, Ops);
    }
    k_lngelu<<<dim3(128), dim3(256), 0, stream>>>(T1, og1, obe1, T1G, 2048, dflag);
    {
        const u16* Aps[2]; float* Ops[2]; size_t Woff[2], b1off[2];
        for (int b = 0; b < 2; b++) {
            Aps[b] = T1G + (size_t)b * 131072;
            Woff[b] = (size_t)b * 2097152;
            b1off[b] = (size_t)b * 1024;
            Ops[b] = T2 + (size_t)b * 65536;
        }
        launch_gemm(1024, 2048, 16, 2, Aps, ow2, Woff, ob2, b1off, nullptr, nullptr, Ops);
    }
    k_final<<<dim3(128), dim3(256), 0, stream>>>(T2, og2, obe2, d_out, dflag);
}

// Round 5
// 1048.497 us; speedup vs baseline: 3.2409x; 3.2409x over previous
//
#include <hip/hip_runtime.h>
#include <hip/hip_bf16.h>
#include <math.h>

typedef unsigned short u16;
typedef unsigned int   u32;
typedef __attribute__((ext_vector_type(8))) short short8;
typedef __attribute__((ext_vector_type(4))) float f32x4;

#define DEV __device__ __forceinline__

DEV float bf2f(u16 x){ u32 u = ((u32)x) << 16; return __builtin_bit_cast(float, u); }
DEV u16 f2bf(float f){ u32 u = __builtin_bit_cast(u32, f); u32 r = (u + 0x7fffu + ((u >> 16) & 1u)) >> 16; return (u16)r; }
DEV float sigf(float x){ return 1.0f / (1.0f + expf(-x)); }
DEV float ldIn(const void* p, size_t i, bool f32){
    return f32 ? ((const float*)p)[i] : bf2f(((const u16*)p)[i]);
}
// device-coherent (L2-bypass, sc0/sc1) accessors for cross-WG data
DEV void stDev(float* p, float v){ __hip_atomic_store(p, v, __ATOMIC_RELAXED, __HIP_MEMORY_SCOPE_AGENT); }
DEV float ldDev(const float* p){ return __hip_atomic_load(p, __ATOMIC_RELAXED, __HIP_MEMORY_SCOPE_AGENT); }
DEV void stFlag(u32* p, u32 v){ __hip_atomic_store(p, v, __ATOMIC_RELAXED, __HIP_MEMORY_SCOPE_AGENT); }
DEV u32 ldFlag(const u32* p){ return __hip_atomic_load(p, __ATOMIC_RELAXED, __HIP_MEMORY_SCOPE_AGENT); }

// -------------------------------------------------------------- k_detect ----
// fp32-vs-bf16 input detect (see r1 analysis) + zero the 8192 barrier flags.
__global__ void k_detect(const u16* __restrict__ pemb, u32* __restrict__ flag,
                         u32* __restrict__ flags)
{
    __shared__ int s;
    if (threadIdx.x == 0) s = 0;
    __syncthreads();
    for (int i = threadIdx.x; i < 4096; i += 256) {
        u16 v = pemb[i];
        int e = (v >> 7) & 0xFF;
        if (e >= 0x90) s = 1;
    }
    __syncthreads();
    if (threadIdx.x == 0) flag[0] = (u32)s;
    for (int i = threadIdx.x; i < 8192; i += 256)
        stFlag(flags + i, 0u);
}

// ---------------------------------------------------------------- k_init ----
__global__ void k_init(const void* __restrict__ pemb, const void* __restrict__ semb,
                       u16* __restrict__ X, const u32* __restrict__ dflag)
{
    bool f32 = dflag[0] != 0u;
    int idx = blockIdx.x * 256 + threadIdx.x;      // 4*64*1024
    int c = idx >> 16;
    int rem = idx & 65535;
    int t = rem >> 10;
    int k = rem & 1023;
    int tsrc = (c < 2) ? t : (63 - t);
    float div = expf(-9.210340371976184f * (float)(k & ~1) / 1024.0f);
    float ang = (float)tsrc * div;
    float pe = (k & 1) ? cosf(ang) : sinf(ang);
    const void* e = (c & 1) ? semb : pemb;
    float v = ldIn(e, (size_t)tsrc * 1024 + k, f32) + pe;
    X[idx] = f2bf(v);
}

// ---------------------------------------------------------------- k_gemm ----
struct GemmArgs {
    const u16* A[8];
    float* O[8];
    size_t Woff[8], b1off[8], b2off[8];
    int hasb2;
    const void *Wb, *b1b, *b2b;
    const u32* flag;
    int N, K, tiles;
};

__global__ __launch_bounds__(256) void k_gemm(GemmArgs g)
{
    bool f32 = g.flag[0] != 0u;
    int b  = blockIdx.x / g.tiles;
    int n0 = (blockIdx.x % g.tiles) * 64;
    int wave = threadIdx.x >> 6, lane = threadIdx.x & 63;
    int ncol = n0 + wave * 16 + (lane & 15);
    int krow = (lane >> 4) * 8;
    const int K = g.K, N = g.N;
    const u16* ap = g.A[b] + (size_t)(lane & 15) * K + krow;
    size_t welem = g.Woff[b] + (size_t)ncol * K + krow;
    const u16*   wp  = ((const u16*)g.Wb)   + welem;
    const float* wpf = ((const float*)g.Wb) + welem;
    f32x4 acc[4] = {};
    for (int k = 0; k < K; k += 32) {
        short8 bfrag;
        if (!f32) {
            bfrag = *(const short8*)(wp + k);
        } else {
            const float* s = wpf + k;
            #pragma unroll
            for (int e = 0; e < 8; e++) bfrag[e] = (short)f2bf(s[e]);
        }
        #pragma unroll
        for (int mt = 0; mt < 4; mt++) {
            short8 afrag = *(const short8*)(ap + (size_t)mt * 16 * K + k);
            acc[mt] = __builtin_amdgcn_mfma_f32_16x16x32_bf16(afrag, bfrag, acc[mt], 0, 0, 0);
        }
    }
    float bias = ldIn(g.b1b, g.b1off[b] + ncol, f32)
               + (g.hasb2 ? ldIn(g.b2b, g.b2off[b] + ncol, f32) : 0.0f);
    float* O = g.O[b];
    #pragma unroll
    for (int mt = 0; mt < 4; mt++) {
        #pragma unroll
        for (int r = 0; r < 4; r++) {
            int m = mt * 16 + (lane >> 4) * 4 + r;
            O[(size_t)m * N + ncol] = acc[mt][r] + bias;
        }
    }
}

// ----------------------------------------------------------------- k_rec ----
// Persistent LSTM recurrence, one layer. 4 groups x 32 WGs.
// Sync: distributed per-WG flag (own 128B line), relaxed agent-scope (sc0/sc1,
// L2-bypass) stores/loads for all cross-WG data -> NO threadfence, NO wbl2,
// NO atomic-RMW contention. h ping-pongs through hbuf via IF$.
// Protocol: iter s waits all group flags >= s+1; reads buf s&1; writes
// buf (s+1)&1; publishes flag = s+2. Initial: zero buf0, publish 1.
__global__ __launch_bounds__(256, 1) void k_rec(const void* __restrict__ WhhV,
        const float* __restrict__ IH, float* __restrict__ hbuf,
        u32* __restrict__ flags, u16* __restrict__ Y, int layer,
        const u32* __restrict__ dflag)
{
    bool f32 = dflag[0] != 0u;
    const int tid = threadIdx.x;
    const int g   = blockIdx.x >> 5;     // 0..3  (m = g>>1, d = g&1)
    const int w   = blockIdx.x & 31;     // h-indices [w*16, w*16+16)
    const int m_  = g >> 1, d = g & 1;
    u32* myflag = flags + (size_t)(layer * 128 + blockIdx.x) * 32;   // 128B stride

    // padded LDS: lds_h[chain][kq*68+off] -> bank = 4*kq + .. (conflict-free)
    __shared__ __align__(16) float lds_h[2 * 544];
    __shared__ float zp[2 * 520];        // [ch][kq*65 + row]  (<=2-way)
    __shared__ float zfin[128];

    // --- weight slice -> registers ---
    const int kq = tid & 7;
    const int rp = tid >> 3;
    const int lr0 = rp * 2, lr1 = rp * 2 + 1;
    const size_t wbase = (size_t)((m_ * 2 + layer) * 2 + d) * 2048 * 512;
    float wf0[64], wf1[64];
    {
        int grow0 = (lr0 >> 4) * 512 + w * 16 + (lr0 & 15);
        int grow1 = (lr1 >> 4) * 512 + w * 16 + (lr1 & 15);
        size_t o0 = wbase + (size_t)grow0 * 512 + kq * 64;
        size_t o1 = wbase + (size_t)grow1 * 512 + kq * 64;
        if (!f32) {
            const u16* s0 = (const u16*)WhhV + o0;
            const u16* s1 = (const u16*)WhhV + o1;
            #pragma unroll
            for (int j8 = 0; j8 < 8; j8++) {
                short8 v0 = *(const short8*)(s0 + j8 * 8);
                short8 v1 = *(const short8*)(s1 + j8 * 8);
                #pragma unroll
                for (int e = 0; e < 8; e++) {
                    wf0[j8 * 8 + e] = bf2f((u16)v0[e]);
                    wf1[j8 * 8 + e] = bf2f((u16)v1[e]);
                }
            }
        } else {
            const float* s0 = (const float*)WhhV + o0;
            const float* s1 = (const float*)WhhV + o1;
            #pragma unroll
            for (int j = 0; j < 64; j++) { wf0[j] = s0[j]; wf1[j] = s1[j]; }
        }
    }
    float cst = 0.0f;

    // zero our slice of ping buffer 0, publish phase 1
    if (tid < 32) {
        int ch = tid >> 4, hh = tid & 15;
        stDev(&hbuf[(0 * 4 + g) * 1024 + ch * 512 + w * 16 + hh], 0.0f);
    }
    __syncthreads();                       // drains vmcnt(0) of wave 0
    if (tid == 0) stFlag(myflag, 1u);

    for (int s = 0; s < 64; s++) {
        int t = d ? (63 - s) : s;
        // --- barrier: wave 0 polls the group's 32 distributed flags ---
        if (tid < 64) {
            const u32* fp = flags + (size_t)(layer * 128 + g * 32 + (tid & 31)) * 32;
            u32 target = (u32)(s + 1);
            while (true) {
                u32 v = ldFlag(fp);
                if (__ballot(v >= target) == ~0ull) break;
                __builtin_amdgcn_s_sleep(1);
            }
        }
        __syncthreads();

        // --- h (both chains) -> padded LDS, via L2-bypass loads ---
        {
            const float* hb = hbuf + ((s & 1) * 4 + g) * 1024;
            int idx4 = tid * 4;
            float4 hv;
            hv.x = ldDev(hb + idx4 + 0);
            hv.y = ldDev(hb + idx4 + 1);
            hv.z = ldDev(hb + idx4 + 2);
            hv.w = ldDev(hb + idx4 + 3);
            int chain = idx4 >> 9, rem = idx4 & 511;
            int dst = chain * 544 + (rem >> 6) * 68 + (rem & 63);
            *(float4*)(&lds_h[dst]) = hv;
        }
        __syncthreads();

        // --- partial dots: 2 rows x 2 chains x 64 k ---
        float a00 = 0, a01 = 0, a10 = 0, a11 = 0;
        {
            const float* h0 = lds_h + kq * 68;
            const float* h1 = lds_h + 544 + kq * 68;
            #pragma unroll
            for (int j4 = 0; j4 < 16; j4++) {
                float4 hv0 = *(const float4*)(h0 + j4 * 4);
                float4 hv1 = *(const float4*)(h1 + j4 * 4);
                int j = j4 * 4;
                a00 += wf0[j]*hv0.x + wf0[j+1]*hv0.y + wf0[j+2]*hv0.z + wf0[j+3]*hv0.w;
                a01 += wf0[j]*hv1.x + wf0[j+1]*hv1.y + wf0[j+2]*hv1.z + wf0[j+3]*hv1.w;
                a10 += wf1[j]*hv0.x + wf1[j+1]*hv0.y + wf1[j+2]*hv0.z + wf1[j+3]*hv0.w;
                a11 += wf1[j]*hv1.x + wf1[j+1]*hv1.y + wf1[j+2]*hv1.z + wf1[j+3]*hv1.w;
            }
        }
        zp[0 * 520 + kq * 65 + lr0] = a00;
        zp[1 * 520 + kq * 65 + lr0] = a01;
        zp[0 * 520 + kq * 65 + lr1] = a10;
        zp[1 * 520 + kq * 65 + lr1] = a11;
        __syncthreads();

        // --- combine + add ih ---
        if (tid < 128) {
            int ch = tid >> 6, lr = tid & 63;
            float z = 0;
            #pragma unroll
            for (int q8 = 0; q8 < 8; q8++) z += zp[ch * 520 + q8 * 65 + lr];
            int b = (2 * m_ + ch) * 2 + d;
            int row = (lr >> 4) * 512 + w * 16 + (lr & 15);
            z += IH[((size_t)(b * 64 + t)) * 2048 + row];
            zfin[ch * 64 + lr] = z;
        }
        __syncthreads();

        // --- gate update + publish (all in wave 0 -> program order + barrier) ---
        if (tid < 32) {
            int ch = tid >> 4, hh = tid & 15;
            float zi = zfin[ch * 64 + hh];
            float zf = zfin[ch * 64 + 16 + hh];
            float zg = zfin[ch * 64 + 32 + hh];
            float zo = zfin[ch * 64 + 48 + hh];
            cst = sigf(zf) * cst + sigf(zi) * tanhf(zg);
            float hv = sigf(zo) * tanhf(cst);
            stDev(&hbuf[(((s + 1) & 1) * 4 + g) * 1024 + ch * 512 + w * 16 + hh], hv);
            Y[(size_t)(2 * m_ + ch) * 65536 + (size_t)t * 1024 + d * 512 + w * 16 + hh] = f2bf(hv);
        }
        __syncthreads();                   // drains wave-0 vmcnt before publish
        if (tid == 0) stFlag(myflag, (u32)(s + 2));
    }
}

// ---------------------------------------------------------------- k_pack ----
__global__ void k_pack(const u16* __restrict__ Y1, u16* __restrict__ GCAT)
{
    int idx = blockIdx.x * 256 + threadIdx.x;     // 2*64*2048
    int g = idx >> 17;
    int rem = idx & 131071;
    int t = rem >> 11;
    int k = rem & 2047;
    u16 v;
    if (k < 1024) v = Y1[(size_t)g * 65536 + (size_t)t * 1024 + k];
    else          v = Y1[(size_t)(g + 2) * 65536 + (size_t)(63 - t) * 1024 + (k - 1024)];
    GCAT[idx] = v;
}

// ------------------------------------------------------------- row stats ----
DEV void rowStats(const float* x, int Nf, float& mean, float& inv)
{
    float s = 0, ss = 0;
    for (int i = threadIdx.x; i < Nf; i += 256) { float v = x[i]; s += v; ss += v * v; }
    for (int o = 32; o > 0; o >>= 1) { s += __shfl_down(s, o, 64); ss += __shfl_down(ss, o, 64); }
    __shared__ float red[8];
    int wave = threadIdx.x >> 6, lane = threadIdx.x & 63;
    if (lane == 0) { red[wave] = s; red[4 + wave] = ss; }
    __syncthreads();
    s  = red[0] + red[1] + red[2] + red[3];
    ss = red[4] + red[5] + red[6] + red[7];
    mean = s / (float)Nf;
    float var = ss / (float)Nf - mean * mean;
    inv = 1.0f / sqrtf(var + 1e-5f);
    __syncthreads();
}

// ------------------------------------------------------------- k_lngelu -----
__global__ __launch_bounds__(256) void k_lngelu(const float* __restrict__ X,
        const void* __restrict__ gg, const void* __restrict__ bb,
        u16* __restrict__ out, int Nf, const u32* __restrict__ dflag)
{
    bool f32 = dflag[0] != 0u;
    int row = blockIdx.x;
    const float* xr = X + (size_t)row * Nf;
    size_t gbase = (size_t)(row >> 6) * Nf;
    float mean, inv;
    rowStats(xr, Nf, mean, inv);
    for (int i = threadIdx.x; i < Nf; i += 256) {
        float y = (xr[i] - mean) * inv * ldIn(gg, gbase + i, f32) + ldIn(bb, gbase + i, f32);
        float a = 0.5f * y * (1.0f + erff(y * 0.70710678118654752f));
        out[(size_t)row * Nf + i] = f2bf(a);
    }
}

// ----------------------------------------------------------- k_gatecomb -----
__global__ void k_gatecomb(const float* __restrict__ GZ, const u16* __restrict__ GCAT,
                           u16* __restrict__ BI)
{
    int idx = blockIdx.x * 256 + threadIdx.x;   // 2*64*1024
    int g = idx >> 16;
    int rem = idx & 65535;
    int t = rem >> 10;
    int k = rem & 1023;
    const float* zr = GZ + (size_t)(g * 64 + t) * 2048;
    const u16* gr = GCAT + (size_t)(g * 64 + t) * 2048;
    float v = sigf(zr[k]) * bf2f(gr[k]) + sigf(zr[1024 + k]) * bf2f(gr[1024 + k]);
    BI[idx] = f2bf(v);
}

// ---------------------------------------------------------------- k_attn ----
__global__ __launch_bounds__(256) void k_attn(const float* __restrict__ QKV, u16* __restrict__ AO)
{
    int a = blockIdx.x >> 3;
    int h = blockIdx.x & 7;
    int tid = threadIdx.x;
    __shared__ u16 kls[64 * 136];
    __shared__ u16 vls[64 * 136];
    __shared__ float sls[64 * 66];

    for (int idx = tid; idx < 8192; idx += 256) {
        int n = idx >> 7, dd = idx & 127;
        kls[n * 136 + dd] = f2bf(QKV[((size_t)((a * 3 + 1) * 64 + n)) * 1024 + h * 128 + dd]);
        vls[n * 136 + dd] = f2bf(QKV[((size_t)((a * 3 + 2) * 64 + n)) * 1024 + h * 128 + dd]);
    }
    __syncthreads();
    {
        int n = tid >> 2, ms = tid & 3;
        const float* qrow = QKV + ((size_t)((a * 3 + 0) * 64 + n)) * 1024 + h * 128;
        float4 qreg[32];
        #pragma unroll
        for (int q4 = 0; q4 < 32; q4++) qreg[q4] = *(const float4*)(qrow + q4 * 4);
        for (int j = 0; j < 16; j++) {
            int m = ms * 16 + j;
            const u16* kr = kls + m * 136;
            float acc = 0;
            #pragma unroll
            for (int q4 = 0; q4 < 32; q4++) {
                u32 k01 = *(const u32*)(kr + q4 * 4);
                u32 k23 = *(const u32*)(kr + q4 * 4 + 2);
                float4 qv = qreg[q4];
                acc += qv.x * bf2f((u16)(k01 & 0xffff)) + qv.y * bf2f((u16)(k01 >> 16))
                     + qv.z * bf2f((u16)(k23 & 0xffff)) + qv.w * bf2f((u16)(k23 >> 16));
            }
            sls[n * 66 + m] = acc * 0.08838834764831845f;
        }
    }
    __syncthreads();
    if (tid < 64) {
        float mx = -1e30f;
        for (int m = 0; m < 64; m++) mx = fmaxf(mx, sls[tid * 66 + m]);
        float sum = 0;
        for (int m = 0; m < 64; m++) { float e = expf(sls[tid * 66 + m] - mx); sls[tid * 66 + m] = e; sum += e; }
        float r = 1.0f / sum;
        for (int m = 0; m < 64; m++) sls[tid * 66 + m] *= r;
    }
    __syncthreads();
    {
        int n = tid & 63, db = tid >> 6;
        float acc[32] = {};
        for (int m = 0; m < 64; m++) {
            float p = sls[n * 66 + m];
            const u16* vr = vls + m * 136 + db * 32;
            #pragma unroll
            for (int jj = 0; jj < 16; jj++) {
                u32 vv = *(const u32*)(vr + jj * 2);
                acc[2 * jj]     += p * bf2f((u16)(vv & 0xffff));
                acc[2 * jj + 1] += p * bf2f((u16)(vv >> 16));
            }
        }
        #pragma unroll
        for (int dd = 0; dd < 32; dd++)
            AO[((size_t)(a * 64 + n)) * 1024 + h * 128 + db * 32 + dd] = f2bf(acc[dd]);
    }
}

// --------------------------------------------------------------- k_resln ----
__global__ __launch_bounds__(256) void k_resln(const u16* __restrict__ BI, const float* __restrict__ PA,
        const void* __restrict__ lg, const void* __restrict__ lb,
        u16* __restrict__ RO, const u32* __restrict__ dflag)
{
    bool f32 = dflag[0] != 0u;
    int row = blockIdx.x;   // 0..127
    __shared__ __align__(16) float xb[1024];
    for (int i = threadIdx.x; i < 1024; i += 256)
        xb[i] = bf2f(BI[(size_t)row * 1024 + i]) + PA[(size_t)row * 1024 + i];
    __syncthreads();
    float mean, inv;
    rowStats(xb, 1024, mean, inv);
    for (int i = threadIdx.x; i < 1024; i += 256) {
        float y = (xb[i] - mean) * inv * ldIn(lg, i, f32) + ldIn(lb, i, f32);
        RO[(size_t)row * 1024 + i] = f2bf(y);
    }
}

// --------------------------------------------------------------- k_final ----
__global__ __launch_bounds__(256) void k_final(const float* __restrict__ T2,
        const void* __restrict__ g2, const void* __restrict__ be2,
        void* __restrict__ dout, const u32* __restrict__ dflag)
{
    bool f32 = dflag[0] != 0u;
    int row = blockIdx.x;         // 0..127  (i = row>>6, t = row&63)
    int i = row >> 6, trow = row & 63;
    const float* xr = T2 + (size_t)row * 1024;
    float mean, inv;
    rowStats(xr, 1024, mean, inv);
    __shared__ __align__(16) float lrow[1024];
    for (int k = threadIdx.x; k < 1024; k += 256) {
        float y = (xr[k] - mean) * inv * ldIn(g2, (size_t)i * 1024 + k, f32)
                + ldIn(be2, (size_t)i * 1024 + k, f32);
        lrow[k] = y;
    }
    __syncthreads();
    size_t base = (size_t)i * 4194304 + (size_t)trow * 1024 + threadIdx.x * 4;
    if (f32) {
        float4 val = *(const float4*)(lrow + threadIdx.x * 4);
        float* df = (float*)dout;
        for (int b = 0; b < 64; b++)
            *(float4*)(df + base + (size_t)b * 65536) = val;
    } else {
        ushort4 val;
        val.x = f2bf(lrow[threadIdx.x * 4 + 0]);
        val.y = f2bf(lrow[threadIdx.x * 4 + 1]);
        val.z = f2bf(lrow[threadIdx.x * 4 + 2]);
        val.w = f2bf(lrow[threadIdx.x * 4 + 3]);
        u16* du = (u16*)dout;
        for (int b = 0; b < 64; b++)
            *(ushort4*)(du + base + (size_t)b * 65536) = val;
    }
}

// ------------------------------------------------------------------ host ----
extern "C" void kernel_launch(void* const* d_in, const int* in_sizes, int n_in,
                              void* d_out, int out_size, void* d_ws, size_t ws_size,
                              hipStream_t stream)
{
    const void* pemb = d_in[0];
    const void* semb = d_in[1];
    const void* Wih  = d_in[2];
    const void* Whh  = d_in[3];
    const void* bih  = d_in[4];
    const void* bhh  = d_in[5];
    const void* attw = d_in[6];
    const void* attb = d_in[7];
    const void* gw1  = d_in[8];
    const void* gb1  = d_in[9];
    const void* glg  = d_in[10];
    const void* glb  = d_in[11];
    const void* gw2  = d_in[12];
    const void* gb2  = d_in[13];
    const void* ow1  = d_in[14];
    const void* ob1  = d_in[15];
    const void* og1  = d_in[16];
    const void* obe1 = d_in[17];
    const void* ow2  = d_in[18];
    const void* ob2  = d_in[19];
    const void* og2  = d_in[20];
    const void* obe2 = d_in[21];
    const void* lng  = d_in[22];
    const void* lnb  = d_in[23];

    char* wsb = (char*)d_ws;
    u32*   dflag= (u32*)  (wsb + 0);
    u32*   flags= (u32*)  (wsb + 256);        // 8192 u32 (2 layers x 128 WG x 32)
    float* hbuf = (float*)(wsb + 33024);      // 32 KB
    u16*   X    = (u16*)  (wsb + 65792);      // 512 KB
    u16*   Y0   = (u16*)  (wsb + 590080);
    u16*   Y1   = (u16*)  (wsb + 1114368);
    float* IHf  = (float*)(wsb + 1638656);    // 4 MB (dead after 2nd k_rec)
    float* T1   = (float*)(wsb + 1638656);    // reuse IHf region
    u16*   T1G  = (u16*)  (wsb + 2687232);
    float* T2   = (float*)(wsb + 3211520);
    u16*   GCAT = (u16*)  (wsb + 5832960);
    float* H1   = (float*)(wsb + 6357248);
    u16*   H1G  = (u16*)  (wsb + 6881536);
    float* GZ   = (float*)(wsb + 7143680);
    u16*   BI   = (u16*)  (wsb + 8192256);
    float* QKVf = (float*)(wsb + 8454400);
    u16*   AO   = (u16*)  (wsb + 10027264);
    float* PA   = (float*)(wsb + 10289408);
    u16*   RO   = (u16*)  (wsb + 10813696);

    auto launch_gemm = [&](int N, int K, int tiles, int nb,
                           const u16* const* Aps,
                           const void* Wbase, const size_t* Woff,
                           const void* b1base, const size_t* b1off,
                           const void* b2base, const size_t* b2off,
                           float* const* Ops)
    {
        GemmArgs ga;
        ga.N = N; ga.K = K; ga.tiles = tiles; ga.flag = dflag;
        ga.Wb = Wbase; ga.b1b = b1base; ga.b2b = b2base;
        ga.hasb2 = (b2base != nullptr) ? 1 : 0;
        for (int b = 0; b < nb; b++) {
            ga.A[b] = Aps[b]; ga.O[b] = Ops[b];
            ga.Woff[b] = Woff[b];
            ga.b1off[b] = b1off[b];
            ga.b2off[b] = b2off ? b2off[b] : 0;
        }
        for (int b = nb; b < 8; b++) {
            ga.A[b] = Aps[0]; ga.O[b] = Ops[0];
            ga.Woff[b] = 0; ga.b1off[b] = 0; ga.b2off[b] = 0;
        }
        k_gemm<<<dim3(nb * tiles), dim3(256), 0, stream>>>(ga);
    };

    // 0) dtype detect + flag zero
    k_detect<<<dim3(1), dim3(256), 0, stream>>>((const u16*)pemb, dflag, flags);

    // 1) embeddings + PE
    k_init<<<dim3(1024), dim3(256), 0, stream>>>(pemb, semb, X, dflag);

    // 2) layer-0 input GEMMs
    {
        const u16* Aps[8]; float* Ops[8]; size_t Woff[8], b1off[8], b2off[8];
        for (int b = 0; b < 8; b++) {
            int c = b >> 1, d = b & 1, m = c >> 1;
            size_t widx = (size_t)(m * 2 + 0) * 2 + d;
            Aps[b] = X + (size_t)c * 65536;
            Woff[b] = widx * 2048 * 1024;
            b1off[b] = widx * 2048;
            b2off[b] = widx * 2048;
            Ops[b] = IHf + (size_t)b * 131072;
        }
        launch_gemm(2048, 1024, 32, 8, Aps, Wih, Woff, bih, b1off, bhh, b2off, Ops);
    }
    // 3) layer-0 recurrence
    k_rec<<<dim3(128), dim3(256), 0, stream>>>(Whh, IHf, hbuf, flags, Y0, 0, dflag);

    // 4) layer-1 input GEMMs
    {
        const u16* Aps[8]; float* Ops[8]; size_t Woff[8], b1off[8], b2off[8];
        for (int b = 0; b < 8; b++) {
            int c = b >> 1, d = b & 1, m = c >> 1;
            size_t widx = (size_t)(m * 2 + 1) * 2 + d;
            Aps[b] = Y0 + (size_t)c * 65536;
            Woff[b] = widx * 2048 * 1024;
            b1off[b] = widx * 2048;
            b2off[b] = widx * 2048;
            Ops[b] = IHf + (size_t)b * 131072;
        }
        launch_gemm(2048, 1024, 32, 8, Aps, Wih, Woff, bih, b1off, bhh, b2off, Ops);
    }
    // 5) layer-1 recurrence
    k_rec<<<dim3(128), dim3(256), 0, stream>>>(Whh, IHf, hbuf, flags, Y1, 1, dflag);

    // 6) gate stage
    k_pack<<<dim3(1024), dim3(256), 0, stream>>>(Y1, GCAT);
    {
        const u16* Aps[2]; float* Ops[2]; size_t Woff[2], b1off[2];
        for (int b = 0; b < 2; b++) {
            Aps[b] = GCAT + (size_t)b * 131072;
            Woff[b] = (size_t)b * 2097152;
            b1off[b] = (size_t)b * 1024;
            Ops[b] = H1 + (size_t)b * 65536;
        }
        launch_gemm(1024, 2048, 16, 2, Aps, gw1, Woff, gb1, b1off, nullptr, nullptr, Ops);
    }
    k_lngelu<<<dim3(128), dim3(256), 0, stream>>>(H1, glg, glb, H1G, 1024, dflag);
    {
        const u16* Aps[2]; float* Ops[2]; size_t Woff[2], b1off[2];
        for (int b = 0; b < 2; b++) {
            Aps[b] = H1G + (size_t)b * 65536;
            Woff[b] = (size_t)b * 2097152;
            b1off[b] = (size_t)b * 2048;
            Ops[b] = GZ + (size_t)b * 131072;
        }
        launch_gemm(2048, 1024, 32, 2, Aps, gw2, Woff, gb2, b1off, nullptr, nullptr, Ops);
    }
    k_gatecomb<<<dim3(512), dim3(256), 0, stream>>>(GZ, GCAT, BI);

    // 7) cross attention
    {
        const u16* Aps[6]; float* Ops[6]; size_t Woff[6], b1off[6];
        for (int aa = 0; aa < 2; aa++) for (int wch = 0; wch < 3; wch++) {
            int b = aa * 3 + wch;
            Aps[b] = BI + (size_t)((wch == 0) ? aa : (1 - aa)) * 65536;
            Woff[b] = (size_t)(aa * 4 + wch) * 1048576;
            b1off[b] = (size_t)(aa * 4 + wch) * 1024;
            Ops[b] = QKVf + (size_t)b * 65536;
        }
        launch_gemm(1024, 1024, 16, 6, Aps, attw, Woff, attb, b1off, nullptr, nullptr, Ops);
    }
    k_attn<<<dim3(16), dim3(256), 0, stream>>>(QKVf, AO);
    {
        const u16* Aps[2]; float* Ops[2]; size_t Woff[2], b1off[2];
        for (int b = 0; b < 2; b++) {
            Aps[b] = AO + (size_t)b * 65536;
            Woff[b] = (size_t)(b * 4 + 3) * 1048576;
            b1off[b] = (size_t)(b * 4 + 3) * 1024;
            Ops[b] = PA + (size_t)b * 65536;
        }
        launch_gemm(1024, 1024, 16, 2, Aps, attw, Woff, attb, b1off, nullptr, nullptr, Ops);
    }
    k_resln<<<dim3(128), dim3(256), 0, stream>>>(BI, PA, lng, lnb, RO, dflag);

    // 8) output transforms
    {
        const u16* Aps[2]; float* Ops[2]; size_t Woff[2], b1off[2];
        for (int b = 0; b < 2; b++) {
            Aps[b] = RO + (size_t)b * 65536;
            Woff[b] = (size_t)b * 2097152;
            b1off[b] = (size_t)b * 2048;
            Ops[b] = T1 + (size_t)b * 131072;
        }
        launch_gemm(2048, 1024, 32, 2, Aps, ow1, Woff, ob1, b1off, nullptr, nullptr, Ops);
    }
    k_lngelu<<<dim3(128), dim3(256), 0, stream>>>(T1, og1, obe1, T1G, 2048, dflag);
    {
        const u16* Aps[2]; float* Ops[2]; size_t Woff[2], b1off[2];
        for (int b = 0; b < 2; b++) {
            Aps[b] = T1G + (size_t)b * 131072;
            Woff[b] = (size_t)b * 2097152;
            b1off[b] = (size_t)b * 1024;
            Ops[b] = T2 + (size_t)b * 65536;
        }
        launch_gemm(1024, 2048, 16, 2, Aps, ow2, Woff, ob2, b1off, nullptr, nullptr, Ops);
    }
    k_final<<<dim3(128), dim3(256), 0, stream>>>(T2, og2, obe2, d_out, dflag);
}